// Round 1
// baseline (621.797 us; speedup 1.0000x reference)
//
#include <hip/hip_runtime.h>
#include <math.h>

#define NPG   256      // nodes per graph
#define EPG   4096     // edges per graph
#define NG    512      // graphs
#define FIN   128
#define HD    64
#define TOUT  18
#define KTOP  16
#define ST    65       // padded LDS row stride (bank-conflict-free)
#define E_TOT (NG*EPG)

__launch_bounds__(256, 1)
__global__ void dgcnn_fused(
    const float* __restrict__ x,
    const int*   __restrict__ ei,
    const float* __restrict__ w0, const float* __restrict__ b0,
    const float* __restrict__ w1, const float* __restrict__ b1,
    const float* __restrict__ w2, const float* __restrict__ b2,
    const float* __restrict__ w3, const float* __restrict__ b3,
    const float* __restrict__ w4, const float* __restrict__ b4,
    const float* __restrict__ c1w, const float* __restrict__ c1b,
    const float* __restrict__ c2w, const float* __restrict__ c2b,
    const float* __restrict__ d1w, const float* __restrict__ d1b,
    const float* __restrict__ d2w, const float* __restrict__ d2b,
    float* __restrict__ out)
{
    __shared__ __align__(16) float s_hl[NPG*ST];    // linear out / wT staging / proj store
    __shared__ __align__(16) float s_hc[NPG*ST];    // current h / x staging
    __shared__ __align__(16) float s_c1wT[257*16];  // conv1 weight transposed [257][16]
    __shared__ int   s_off[NPG+1];
    __shared__ int   s_cur[NPG];
    __shared__ int   s_outd[NPG];
    __shared__ unsigned char s_srcl[EPG];           // CSR-by-dst: local src ids
    __shared__ float s_invdeg[NPG];
    __shared__ float s_h5[NPG];
    __shared__ int   s_sel[KTOP];
    __shared__ float s_w4[HD];
    __shared__ __align__(16) float s_head[592];

    const int g    = blockIdx.x;
    const int t    = threadIdx.x;
    const int lane = t & 63;
    const int wid  = t >> 6;
    const int gbase = g * NPG;

    const int* srcg = ei + (size_t)g * EPG;
    const int* dstg = ei + (size_t)E_TOT + (size_t)g * EPG;

    // ---------------- CSR build (by dst) + degrees ----------------
    s_cur[t]  = 0;
    s_outd[t] = 0;
    if (t < HD) s_w4[t] = w4[t];
    for (int i = t; i < 257*16; i += 256) {          // stage conv1_w transposed
        int o = i & 15, d = i >> 4;
        s_c1wT[i] = c1w[o*257 + d];
    }
    __syncthreads();
    for (int e = t; e < EPG; e += 256) {
        int s = srcg[e] - gbase;
        int d = dstg[e] - gbase;
        atomicAdd(&s_outd[s], 1);
        atomicAdd(&s_cur[d], 1);                     // indeg counts (temp)
    }
    __syncthreads();
    s_invdeg[t] = 1.0f / (float)(s_outd[t] + 1);     // norm = 1/(outdeg+1) gathered at dst
    if (t == 0) {
        int acc = 0; s_off[0] = 0;
        for (int i = 0; i < NPG; i++) { acc += s_cur[i]; s_off[i+1] = acc; }
    }
    __syncthreads();
    s_cur[t] = s_off[t];
    __syncthreads();
    for (int e = t; e < EPG; e += 256) {
        int s = srcg[e] - gbase;
        int d = dstg[e] - gbase;
        int pos = atomicAdd(&s_cur[d], 1);
        s_srcl[pos] = (unsigned char)s;
    }
    // (first sync inside layer loop orders this before any use)

    float proj[16];                                  // per-node conv1 projection accum
    #pragma unroll
    for (int o = 0; o < 16; o++) proj[o] = 0.f;

    const int ng = t >> 2;   // node group: nodes ng*4 .. ng*4+3
    const int cg = t & 3;    // channel group: channels cg*16 .. +15

    // ---------------- 4 GCN layers of width 64 ----------------
    #pragma unroll 1
    for (int L = 0; L < 4; L++) {
        const float* w; const float* b;
        switch (L) {
            case 0:  w = w0; b = b0; break;
            case 1:  w = w1; b = b1; break;
            case 2:  w = w2; b = b2; break;
            default: w = w3; b = b3; break;
        }
        const int F = (L == 0) ? FIN : HD;
        const int nchunk = F >> 6;

        float acc[4][16];
        #pragma unroll
        for (int i = 0; i < 4; i++)
            #pragma unroll
            for (int j = 0; j < 16; j++)
                acc[i][j] = b[cg*16 + j];

        for (int ck = 0; ck < nchunk; ck++) {
            __syncthreads();                          // s_hl free (prev readers done)
            // stage wT chunk [64k][64c] into s_hl
            for (int i = t; i < 64*64; i += 256) {
                int k = i >> 6, c = i & 63;
                s_hl[i] = w[c*F + ck*64 + k];
            }
            if (L == 0) {                             // stage x[:, ck*64 .. +64) into s_hc
                const float4* xr = reinterpret_cast<const float4*>(
                    x + (size_t)(gbase + t)*FIN + ck*64);
                #pragma unroll
                for (int q = 0; q < 16; q++) {
                    float4 f = xr[q];
                    s_hc[t*ST + q*4 + 0] = f.x;
                    s_hc[t*ST + q*4 + 1] = f.y;
                    s_hc[t*ST + q*4 + 2] = f.z;
                    s_hc[t*ST + q*4 + 3] = f.w;
                }
            }
            __syncthreads();
            #pragma unroll 4
            for (int k = 0; k < 64; k++) {
                float xv[4];
                #pragma unroll
                for (int i = 0; i < 4; i++) xv[i] = s_hc[(ng*4 + i)*ST + k];
                const float4* wr = reinterpret_cast<const float4*>(&s_hl[k*64 + cg*16]);
                float4 wa = wr[0], wb = wr[1], wc = wr[2], wd = wr[3];
                #pragma unroll
                for (int i = 0; i < 4; i++) {
                    acc[i][0]  += xv[i]*wa.x;  acc[i][1]  += xv[i]*wa.y;
                    acc[i][2]  += xv[i]*wa.z;  acc[i][3]  += xv[i]*wa.w;
                    acc[i][4]  += xv[i]*wb.x;  acc[i][5]  += xv[i]*wb.y;
                    acc[i][6]  += xv[i]*wb.z;  acc[i][7]  += xv[i]*wb.w;
                    acc[i][8]  += xv[i]*wc.x;  acc[i][9]  += xv[i]*wc.y;
                    acc[i][10] += xv[i]*wc.z;  acc[i][11] += xv[i]*wc.w;
                    acc[i][12] += xv[i]*wd.x;  acc[i][13] += xv[i]*wd.y;
                    acc[i][14] += xv[i]*wd.z;  acc[i][15] += xv[i]*wd.w;
                }
            }
        }
        __syncthreads();                              // all reads of s_hl(wT) done
        #pragma unroll
        for (int i = 0; i < 4; i++)
            #pragma unroll
            for (int j = 0; j < 16; j++)
                s_hl[(ng*4 + i)*ST + cg*16 + j] = acc[i][j];
        __syncthreads();

        // aggregation: h[d] = tanh((sum_in hl[src] + hl[d]) / (outdeg(d)+1))
        for (int d = wid; d < NPG; d += 4) {
            float a = s_hl[d*ST + lane];
            int e  = s_off[d];
            int e1 = s_off[d+1];
            for (; e + 4 <= e1; e += 4) {
                int s0a = s_srcl[e],   s1a = s_srcl[e+1];
                int s2a = s_srcl[e+2], s3a = s_srcl[e+3];
                a += s_hl[s0a*ST + lane];
                a += s_hl[s1a*ST + lane];
                a += s_hl[s2a*ST + lane];
                a += s_hl[s3a*ST + lane];
            }
            for (; e < e1; e++) a += s_hl[(int)s_srcl[e]*ST + lane];
            s_hc[d*ST + lane] = tanhf(a * s_invdeg[d]);
        }
        __syncthreads();

        // proj accumulation for this layer's 64 channels (node t)
        const int off = L*64;
        #pragma unroll 8
        for (int c = 0; c < 64; c++) {
            float v = s_hc[t*ST + c];
            const float4* cw = reinterpret_cast<const float4*>(&s_c1wT[(off + c)*16]);
            float4 a0 = cw[0], a1 = cw[1], a2 = cw[2], a3 = cw[3];
            proj[0]+=v*a0.x;  proj[1]+=v*a0.y;  proj[2]+=v*a0.z;  proj[3]+=v*a0.w;
            proj[4]+=v*a1.x;  proj[5]+=v*a1.y;  proj[6]+=v*a1.z;  proj[7]+=v*a1.w;
            proj[8]+=v*a2.x;  proj[9]+=v*a2.y;  proj[10]+=v*a2.z; proj[11]+=v*a2.w;
            proj[12]+=v*a3.x; proj[13]+=v*a3.y; proj[14]+=v*a3.z; proj[15]+=v*a3.w;
        }
    }

    // ---------------- layer 5 (64 -> 1) ----------------
    {
        float a = b4[0];
        #pragma unroll 8
        for (int k = 0; k < HD; k++) a += s_hc[t*ST + k] * s_w4[k];
        s_hl[t] = a;                                  // compact storage
        __syncthreads();
        float accv = s_hl[t];
        int e1 = s_off[t+1];
        for (int e = s_off[t]; e < e1; e++) accv += s_hl[(int)s_srcl[e]];
        float h5 = tanhf(accv * s_invdeg[t]);
        s_h5[t] = h5;
        {
            const float4* cw = reinterpret_cast<const float4*>(&s_c1wT[256*16]);
            float4 a0 = cw[0], a1 = cw[1], a2 = cw[2], a3 = cw[3];
            proj[0]+=h5*a0.x;  proj[1]+=h5*a0.y;  proj[2]+=h5*a0.z;  proj[3]+=h5*a0.w;
            proj[4]+=h5*a1.x;  proj[5]+=h5*a1.y;  proj[6]+=h5*a1.z;  proj[7]+=h5*a1.w;
            proj[8]+=h5*a2.x;  proj[9]+=h5*a2.y;  proj[10]+=h5*a2.z; proj[11]+=h5*a2.w;
            proj[12]+=h5*a3.x; proj[13]+=h5*a3.y; proj[14]+=h5*a3.z; proj[15]+=h5*a3.w;
        }
        __syncthreads();
        #pragma unroll
        for (int o = 0; o < 16; o++) s_hl[t*16 + o] = proj[o];   // s_proj
        __syncthreads();
    }

    // ---------------- top-16 selection (desc value, asc index ties) ----------------
    if (wid == 0) {
        float v[4]; int idx[4];
        #pragma unroll
        for (int j = 0; j < 4; j++) { idx[j] = lane*4 + j; v[j] = s_h5[lane*4 + j]; }
        for (int r = 0; r < KTOP; r++) {
            float bv = v[0]; int bi = idx[0];
            #pragma unroll
            for (int j = 1; j < 4; j++)
                if (v[j] > bv || (v[j] == bv && idx[j] < bi)) { bv = v[j]; bi = idx[j]; }
            #pragma unroll
            for (int o = 32; o > 0; o >>= 1) {
                float ov = __shfl_xor(bv, o);
                int   oi = __shfl_xor(bi, o);
                if (ov > bv || (ov == bv && oi < bi)) { bv = ov; bi = oi; }
            }
            if ((bi >> 2) == lane) v[bi & 3] = -1e30f;
            if (lane == 0) s_sel[r] = bi;
        }
    }
    __syncthreads();

    // ---------------- head ----------------
    float* s_c1   = s_head;        // [16 o][16 l]
    float* s_p1   = s_head + 256;  // [16 o][8 j]
    float* s_flat = s_head + 384;  // 128
    float* s_last = s_head + 512;  // 32
    float* s_outv = s_head + 544;  // 18

    {
        int l = t >> 4, o = t & 15;
        float vv = s_hl[s_sel[l]*16 + o] + c1b[o];
        s_c1[o*16 + l] = fmaxf(vv, 0.f);
    }
    __syncthreads();
    if (t < 128) {
        int o = t >> 3, j = t & 7;
        s_p1[o*8 + j] = fmaxf(s_c1[o*16 + 2*j], s_c1[o*16 + 2*j + 1]);
    }
    __syncthreads();
    if (t < 128) {
        int oc = t >> 2, tt = t & 3;
        float a = c2b[oc];
        #pragma unroll
        for (int ic = 0; ic < 16; ic++)
            #pragma unroll
            for (int kk = 0; kk < 5; kk++)
                a += s_p1[ic*8 + tt + kk] * c2w[(oc*16 + ic)*5 + kk];
        s_flat[oc*4 + tt] = fmaxf(a, 0.f);
    }
    __syncthreads();
    if (t < 32) {
        float a = d1b[t];
        #pragma unroll 16
        for (int i = 0; i < 128; i++) a += s_flat[i] * d1w[t*128 + i];
        a = fmaxf(a, 0.f);
        s_last[t] = a;
        out[2*NG*TOUT + g*32 + t] = a;                 // output 2: last
    }
    __syncthreads();
    if (t < TOUT) {
        float a = d2b[t];
        #pragma unroll
        for (int j = 0; j < 32; j++) a += s_last[j] * d2w[t*32 + j];
        s_outv[t] = a;
        out[NG*TOUT + g*TOUT + t] = a;                 // output 1: logits
    }
    __syncthreads();
    if (t < TOUT) {
        float m = s_outv[0];
        for (int i = 1; i < TOUT; i++) m = fmaxf(m, s_outv[i]);
        float sum = 0.f;
        for (int i = 0; i < TOUT; i++) sum += expf(s_outv[i] - m);
        out[g*TOUT + t] = s_outv[t] - m - logf(sum);   // output 0: log_softmax
    }
}

extern "C" void kernel_launch(void* const* d_in, const int* in_sizes, int n_in,
                              void* d_out, int out_size, void* d_ws, size_t ws_size,
                              hipStream_t stream) {
    (void)in_sizes; (void)n_in; (void)out_size; (void)d_ws; (void)ws_size;
    const float* x   = (const float*)d_in[0];
    const int*   ei  = (const int*)  d_in[1];
    // d_in[2]=batch, d_in[3]=num_graphs (unused: structure is static)
    const float* w0  = (const float*)d_in[4];  const float* b0 = (const float*)d_in[5];
    const float* w1  = (const float*)d_in[6];  const float* b1 = (const float*)d_in[7];
    const float* w2  = (const float*)d_in[8];  const float* b2 = (const float*)d_in[9];
    const float* w3  = (const float*)d_in[10]; const float* b3 = (const float*)d_in[11];
    const float* w4  = (const float*)d_in[12]; const float* b4 = (const float*)d_in[13];
    const float* c1w = (const float*)d_in[14]; const float* c1b = (const float*)d_in[15];
    const float* c2w = (const float*)d_in[16]; const float* c2b = (const float*)d_in[17];
    const float* d1w = (const float*)d_in[18]; const float* d1b = (const float*)d_in[19];
    const float* d2w = (const float*)d_in[20]; const float* d2b = (const float*)d_in[21];
    float* out = (float*)d_out;

    dgcnn_fused<<<NG, 256, 0, stream>>>(x, ei,
        w0, b0, w1, b1, w2, b2, w3, b3, w4, b4,
        c1w, c1b, c2w, c2b, d1w, d1b, d2w, d2b, out);
}

// Round 2
// 180.484 us; speedup vs baseline: 3.4452x; 3.4452x over previous
//
#include <hip/hip_runtime.h>
#include <math.h>

#define NPG  256
#define EPG  4096
#define NG   512
#define FIN  128
#define HD   64
#define TOUT 18
#define KTOP 16
#define STB  260              // B-layout [ch][node] stride
#define STA  68               // A-layout [node][ch] stride
#define SRCL_CAP (EPG + 3*NPG)
#define E_TOT (NG*EPG)

__launch_bounds__(1024)
__global__ void dgcnn_fused(
    const float* __restrict__ x,
    const int*   __restrict__ ei,
    const float* __restrict__ w0, const float* __restrict__ b0,
    const float* __restrict__ w1, const float* __restrict__ b1,
    const float* __restrict__ w2, const float* __restrict__ b2,
    const float* __restrict__ w3, const float* __restrict__ b3,
    const float* __restrict__ w4, const float* __restrict__ b4,
    const float* __restrict__ c1w, const float* __restrict__ c1b,
    const float* __restrict__ c2w, const float* __restrict__ c2b,
    const float* __restrict__ d1w, const float* __restrict__ d1b,
    const float* __restrict__ d2w, const float* __restrict__ d2b,
    float* __restrict__ out)
{
    __shared__ float s_hB[HD*STB];                 // h (post-tanh), transposed [ch][node]
    __shared__ float s_hl[NPG*STA];                // h_lin [node][ch^xor]; later proj store [n][16]
    __shared__ unsigned char s_srcl[SRCL_CAP] __attribute__((aligned(4)));
    __shared__ int   s_off[NPG+1];
    __shared__ int   s_cnt[NPG];
    __shared__ int   s_outd[NPG];
    __shared__ int   s_cur[NPG];
    __shared__ float s_invdeg[NPG];
    __shared__ float s_lin5[NPG];
    __shared__ float s_h5[NPG];
    __shared__ int   s_sel[KTOP];
    __shared__ float s_head[592];

    const int g = blockIdx.x;
    const int t = threadIdx.x;
    const int lane = t & 63;
    const int wid  = t >> 6;
    const int l4 = lane * 4;
    const int gbase = g * NPG;
    const int* __restrict__ srcg = ei + (size_t)g * EPG;
    const int* __restrict__ dstg = ei + (size_t)E_TOT + (size_t)g * EPG;

    // ---------------- phase 0: degrees + 4-padded CSR by dst ----------------
    if (t < NPG) { s_cnt[t] = 0; s_outd[t] = 0; }
    __syncthreads();
    for (int e = t; e < EPG; e += 1024) {
        int s = srcg[e] - gbase, d = dstg[e] - gbase;
        atomicAdd(&s_outd[s], 1);
        atomicAdd(&s_cnt[d], 1);
    }
    __syncthreads();
    if (t < NPG) s_invdeg[t] = 1.0f / (float)(s_outd[t] + 1);
    if (wid == 0) {   // wave-parallel prefix sum of padded counts
        int c0 = s_cnt[l4], c1 = s_cnt[l4+1], c2 = s_cnt[l4+2], c3 = s_cnt[l4+3];
        int p0 = (c0+3)&~3, p1 = (c1+3)&~3, p2 = (c2+3)&~3, p3 = (c3+3)&~3;
        int tot = p0+p1+p2+p3;
        int run = tot;
        #pragma unroll
        for (int o = 1; o < 64; o <<= 1) {
            int v = __shfl_up(run, o);
            if (lane >= o) run += v;
        }
        int base = run - tot;
        s_off[l4]   = base;
        s_off[l4+1] = base + p0;
        s_off[l4+2] = base + p0 + p1;
        s_off[l4+3] = base + p0 + p1 + p2;
        if (lane == 63) s_off[NPG] = run;
    }
    __syncthreads();
    if (t < NPG) s_cur[t] = s_off[t];
    __syncthreads();
    for (int e = t; e < EPG; e += 1024) {
        int s = srcg[e] - gbase, d = dstg[e] - gbase;
        int pos = atomicAdd(&s_cur[d], 1);
        s_srcl[pos] = (unsigned char)s;
    }
    __syncthreads();
    if (t < NPG) {   // pad each list to x4 with sentinel src=d (corrected via 1-npad)
        int pe = s_off[t+1];
        for (int p = s_cur[t]; p < pe; p++) s_srcl[p] = (unsigned char)t;
    }
    __syncthreads();

    float projacc[4][4];
    #pragma unroll
    for (int i = 0; i < 4; i++)
        #pragma unroll
        for (int j = 0; j < 4; j++) projacc[i][j] = 0.f;

    // agg: h[d][c] = tanh(invdeg*(sum_src h_lin[src][c] + h_lin[d][c])), 4 dst/wave
    auto aggregate = [&]() {
        const int js = lane >> 4;
        const int q4 = (lane & 15) * 4;
        for (int job = wid; job < 64; job += 16) {
            int d   = job*4 + js;
            int off = s_off[d], pe = s_off[d+1];
            int npad = (pe - off) - s_cnt[d];
            float4 a = *(const float4*)&s_hl[d*STA + (q4 ^ (((d>>2)&7)<<2))];
            float cf = (float)(1 - npad);
            a.x *= cf; a.y *= cf; a.z *= cf; a.w *= cf;
            for (int e = off; e < pe; e += 4) {
                unsigned int sq = *(const unsigned int*)&s_srcl[e];
                #pragma unroll
                for (int m = 0; m < 4; m++) {
                    int src = (sq >> (8*m)) & 255;
                    float4 hv = *(const float4*)&s_hl[src*STA + (q4 ^ (((src>>2)&7)<<2))];
                    a.x += hv.x; a.y += hv.y; a.z += hv.z; a.w += hv.w;
                }
            }
            float id = s_invdeg[d];
            s_hB[(q4+0)*STB + d] = tanhf(a.x * id);
            s_hB[(q4+1)*STB + d] = tanhf(a.y * id);
            s_hB[(q4+2)*STB + d] = tanhf(a.z * id);
            s_hB[(q4+3)*STB + d] = tanhf(a.w * id);
        }
    };

    // matmul: h_lin[n][c] = sum_k h[k][n]*w[c][k] + b[c]; wave=ch-quad, lane=4 nodes
    auto matmul64 = [&](const float* __restrict__ w, const float* __restrict__ b) {
        const int c0 = __builtin_amdgcn_readfirstlane(wid * 4);
        const float* wp = w + c0 * HD;
        float acc[4][4];
        #pragma unroll
        for (int i = 0; i < 4; i++)
            #pragma unroll
            for (int j = 0; j < 4; j++) acc[i][j] = 0.f;
        #pragma unroll 8
        for (int k = 0; k < HD; k++) {
            float4 xv = *(const float4*)&s_hB[k*STB + l4];
            float wv0 = wp[k], wv1 = wp[HD+k], wv2 = wp[2*HD+k], wv3 = wp[3*HD+k];
            float xa[4] = {xv.x, xv.y, xv.z, xv.w};
            #pragma unroll
            for (int i = 0; i < 4; i++) {
                acc[i][0] += xa[i]*wv0; acc[i][1] += xa[i]*wv1;
                acc[i][2] += xa[i]*wv2; acc[i][3] += xa[i]*wv3;
            }
        }
        float4 bb = *(const float4*)&b[c0];
        float ba[4] = {bb.x, bb.y, bb.z, bb.w};
        int colb = (wid*4) ^ ((lane & 7) << 2);   // XOR swizzle vs 16-way write conflict
        #pragma unroll
        for (int i = 0; i < 4; i++) {
            float4 v;
            v.x = acc[i][0]+ba[0]; v.y = acc[i][1]+ba[1];
            v.z = acc[i][2]+ba[2]; v.w = acc[i][3]+ba[3];
            *(float4*)&s_hl[(l4+i)*STA + colb] = v;
        }
    };

    // conv1 projection accumulation (waves 0-3 only), 16 outputs
    auto projpass = [&](int Loff) {
        const int o0 = __builtin_amdgcn_readfirstlane(wid * 4);
        const float* p = c1w + o0*257 + Loff;
        #pragma unroll 8
        for (int k = 0; k < HD; k++) {
            float4 xv = *(const float4*)&s_hB[k*STB + l4];
            float p0 = p[k], p1 = p[257+k], p2 = p[514+k], p3 = p[771+k];
            float xa[4] = {xv.x, xv.y, xv.z, xv.w};
            #pragma unroll
            for (int i = 0; i < 4; i++) {
                projacc[i][0] += xa[i]*p0; projacc[i][1] += xa[i]*p1;
                projacc[i][2] += xa[i]*p2; projacc[i][3] += xa[i]*p3;
            }
        }
    };

    // ---------------- layer 0 (F=128, x^T staged in 2 chunks) ----------------
    {
        const int c0 = __builtin_amdgcn_readfirstlane(wid * 4);
        float acc[4][4];
        #pragma unroll
        for (int i = 0; i < 4; i++)
            #pragma unroll
            for (int j = 0; j < 4; j++) acc[i][j] = 0.f;
        for (int c2 = 0; c2 < 2; c2++) {
            {   // stage x^T chunk into s_hB
                int kk = (t & 15) * 4, nb = t >> 4;
                #pragma unroll
                for (int r = 0; r < 4; r++) {
                    int nn = nb + r*64;
                    float4 v = *(const float4*)&x[(size_t)(gbase+nn)*FIN + c2*64 + kk];
                    s_hB[(kk+0)*STB + nn] = v.x;
                    s_hB[(kk+1)*STB + nn] = v.y;
                    s_hB[(kk+2)*STB + nn] = v.z;
                    s_hB[(kk+3)*STB + nn] = v.w;
                }
            }
            __syncthreads();
            const float* wp = w0 + c0*FIN + c2*64;
            #pragma unroll 8
            for (int k = 0; k < 64; k++) {
                float4 xv = *(const float4*)&s_hB[k*STB + l4];
                float wv0 = wp[k], wv1 = wp[FIN+k], wv2 = wp[2*FIN+k], wv3 = wp[3*FIN+k];
                float xa[4] = {xv.x, xv.y, xv.z, xv.w};
                #pragma unroll
                for (int i = 0; i < 4; i++) {
                    acc[i][0] += xa[i]*wv0; acc[i][1] += xa[i]*wv1;
                    acc[i][2] += xa[i]*wv2; acc[i][3] += xa[i]*wv3;
                }
            }
            __syncthreads();
        }
        float4 bb = *(const float4*)&b0[c0];
        float ba[4] = {bb.x, bb.y, bb.z, bb.w};
        int colb = (wid*4) ^ ((lane & 7) << 2);
        #pragma unroll
        for (int i = 0; i < 4; i++) {
            float4 v;
            v.x = acc[i][0]+ba[0]; v.y = acc[i][1]+ba[1];
            v.z = acc[i][2]+ba[2]; v.w = acc[i][3]+ba[3];
            *(float4*)&s_hl[(l4+i)*STA + colb] = v;
        }
    }
    __syncthreads();
    aggregate();                       // -> h0
    __syncthreads();

    // ---------------- layers 1..3 (proj of previous layer overlapped) -------
    if (wid < 4) projpass(0);
    matmul64(w1, b1);
    __syncthreads();
    aggregate();                       // -> h1
    __syncthreads();

    if (wid < 4) projpass(64);
    matmul64(w2, b2);
    __syncthreads();
    aggregate();                       // -> h2
    __syncthreads();

    if (wid < 4) projpass(128);
    matmul64(w3, b3);
    __syncthreads();
    aggregate();                       // -> h3
    __syncthreads();

    // ---------------- layer 4 (64->1) + proj3 ----------------
    if (wid < 4) {
        projpass(192);
    } else if (wid < 8) {
        int n = t - 256;
        float a = b4[0];
        #pragma unroll 8
        for (int k = 0; k < HD; k++) a += s_hB[k*STB + n] * w4[k];
        s_lin5[n] = a;
    }
    __syncthreads();
    if (t < NPG) {
        int d = t;
        int off = s_off[d], pe = s_off[d+1];
        int npad = (pe - off) - s_cnt[d];
        float a = (float)(1 - npad) * s_lin5[d];
        for (int e = off; e < pe; e += 4) {
            unsigned int sq = *(const unsigned int*)&s_srcl[e];
            a += s_lin5[sq & 255] + s_lin5[(sq>>8)&255]
               + s_lin5[(sq>>16)&255] + s_lin5[(sq>>24)&255];
        }
        s_h5[d] = tanhf(a * s_invdeg[d]);
    }
    __syncthreads();
    // h5 proj contribution + store proj rows [n][16] into s_hl; topk
    if (wid < 4) {
        const int o0 = __builtin_amdgcn_readfirstlane(wid * 4);
        float cw0 = c1w[(o0+0)*257 + 256];
        float cw1 = c1w[(o0+1)*257 + 256];
        float cw2 = c1w[(o0+2)*257 + 256];
        float cw3 = c1w[(o0+3)*257 + 256];
        #pragma unroll
        for (int i = 0; i < 4; i++) {
            float hv = s_h5[l4+i];
            float4 v;
            v.x = projacc[i][0] + hv*cw0;
            v.y = projacc[i][1] + hv*cw1;
            v.z = projacc[i][2] + hv*cw2;
            v.w = projacc[i][3] + hv*cw3;
            *(float4*)&s_hl[(l4+i)*16 + wid*4] = v;
        }
    }
    if (wid == 0) {   // top-16: desc value, asc index ties
        float v[4]; int idx[4];
        #pragma unroll
        for (int j = 0; j < 4; j++) { idx[j] = l4+j; v[j] = s_h5[l4+j]; }
        for (int r = 0; r < KTOP; r++) {
            float bv = v[0]; int bi = idx[0];
            #pragma unroll
            for (int j = 1; j < 4; j++)
                if (v[j] > bv || (v[j] == bv && idx[j] < bi)) { bv = v[j]; bi = idx[j]; }
            #pragma unroll
            for (int o = 32; o > 0; o >>= 1) {
                float ov = __shfl_xor(bv, o);
                int   oi = __shfl_xor(bi, o);
                if (ov > bv || (ov == bv && oi < bi)) { bv = ov; bi = oi; }
            }
            if ((bi >> 2) == lane) v[bi & 3] = -1e30f;
            if (lane == 0) s_sel[r] = bi;
        }
    }
    __syncthreads();

    // ---------------- head ----------------
    float* s_c1   = s_head;        // [16 o][16 l]
    float* s_p1   = s_head + 256;  // [16 o][8 j]
    float* s_flat = s_head + 384;  // 128
    float* s_last = s_head + 512;  // 32
    float* s_outv = s_head + 544;  // 18

    if (t < 256) {
        int sl = t >> 4, o = t & 15;
        float vv = s_hl[s_sel[sl]*16 + o] + c1b[o];
        s_c1[o*16 + sl] = fmaxf(vv, 0.f);
    }
    __syncthreads();
    if (t < 128) {
        int o = t >> 3, j = t & 7;
        s_p1[o*8 + j] = fmaxf(s_c1[o*16 + 2*j], s_c1[o*16 + 2*j + 1]);
    }
    __syncthreads();
    if (t < 128) {
        int oc = t >> 2, tt = t & 3;
        float a = c2b[oc];
        #pragma unroll
        for (int ic = 0; ic < 16; ic++)
            #pragma unroll
            for (int kk = 0; kk < 5; kk++)
                a += s_p1[ic*8 + tt + kk] * c2w[(oc*16 + ic)*5 + kk];
        s_flat[oc*4 + tt] = fmaxf(a, 0.f);
    }
    __syncthreads();
    if (t < 32) {
        float a = d1b[t];
        #pragma unroll 16
        for (int i = 0; i < 128; i++) a += s_flat[i] * d1w[t*128 + i];
        a = fmaxf(a, 0.f);
        s_last[t] = a;
        out[2*NG*TOUT + g*32 + t] = a;                 // output 2: last
    }
    __syncthreads();
    if (t < TOUT) {
        float a = d2b[t];
        #pragma unroll
        for (int j = 0; j < 32; j++) a += s_last[j] * d2w[t*32 + j];
        s_outv[t] = a;
        out[NG*TOUT + g*TOUT + t] = a;                 // output 1: logits
    }
    __syncthreads();
    if (t < TOUT) {
        float m = s_outv[0];
        for (int i = 1; i < TOUT; i++) m = fmaxf(m, s_outv[i]);
        float sum = 0.f;
        for (int i = 0; i < TOUT; i++) sum += expf(s_outv[i] - m);
        out[g*TOUT + t] = s_outv[t] - m - logf(sum);   // output 0: log_softmax
    }
}

extern "C" void kernel_launch(void* const* d_in, const int* in_sizes, int n_in,
                              void* d_out, int out_size, void* d_ws, size_t ws_size,
                              hipStream_t stream) {
    (void)in_sizes; (void)n_in; (void)out_size; (void)d_ws; (void)ws_size;
    const float* x   = (const float*)d_in[0];
    const int*   ei  = (const int*)  d_in[1];
    const float* w0  = (const float*)d_in[4];  const float* b0 = (const float*)d_in[5];
    const float* w1  = (const float*)d_in[6];  const float* b1 = (const float*)d_in[7];
    const float* w2  = (const float*)d_in[8];  const float* b2 = (const float*)d_in[9];
    const float* w3  = (const float*)d_in[10]; const float* b3 = (const float*)d_in[11];
    const float* w4  = (const float*)d_in[12]; const float* b4 = (const float*)d_in[13];
    const float* c1w = (const float*)d_in[14]; const float* c1b = (const float*)d_in[15];
    const float* c2w = (const float*)d_in[16]; const float* c2b = (const float*)d_in[17];
    const float* d1w = (const float*)d_in[18]; const float* d1b = (const float*)d_in[19];
    const float* d2w = (const float*)d_in[20]; const float* d2b = (const float*)d_in[21];
    float* out = (float*)d_out;

    dgcnn_fused<<<NG, 1024, 0, stream>>>(x, ei,
        w0, b0, w1, b1, w2, b2, w3, b3, w4, b4,
        c1w, c1b, c2w, c2b, d1w, d1b, d2w, d2b, out);
}